// Round 12
// baseline (101.555 us; speedup 1.0000x reference)
//
#include <hip/hip_runtime.h>

#define HID 2048
#define NE 64
#define NTOK 32768        // GROUPS * TOKENS = 4 * 8192
#define CAP 160
#define GAP_THR 0.01f

typedef unsigned short u16;
typedef short bf16x8 __attribute__((ext_vector_type(8)));
typedef float f32x16 __attribute__((ext_vector_type(16)));

typedef __attribute__((address_space(1))) const void gvoid;
typedef __attribute__((address_space(3))) void lvoid;
#define GLOAD_LDS16(gp, lp) \
    __builtin_amdgcn_global_load_lds((gvoid*)(gp), (lvoid*)(lp), 16, 0, 0)

// fp32 -> bf16 hi (truncate) + bf16 lo (truncate of exact remainder).
static __device__ __forceinline__ void cvt8(const float4& a, const float4& b,
                                            bf16x8& hi, bf16x8& lo) {
    float f[8] = {a.x, a.y, a.z, a.w, b.x, b.y, b.z, b.w};
#pragma unroll
    for (int j = 0; j < 8; ++j) {
        const unsigned u = __float_as_uint(f[j]);
        const unsigned h = u >> 16;
        const float r = f[j] - __uint_as_float(h << 16);   // exact
        hi[j] = (short)h;
        lo[j] = (short)(__float_as_uint(r) >> 16);
    }
}

// ---------------------------------------------------------------------------
// K0: split W into bf16 hi/lo, fragment-major: step S (0..127) owns 4KB
// [h0|h1|l0|l1], each chunk 1KB = lane*16B.  S = global K-step = k0/16.
// ---------------------------------------------------------------------------
__global__ void k_wconv(const float* __restrict__ W, u16* __restrict__ Wfrag)
{
    const int idx = blockIdx.x * 256 + threadIdx.x;   // 0..16383
    if (idx >= NE * (HID / 8)) return;
    const int e  = idx >> 8;          // expert 0..63
    const int k0 = (idx & 255) * 8;
    const int S    = k0 >> 4;
    const int khal = (k0 >> 3) & 1;
    const int lane = (e & 31) + khal * 32;

    bf16x8 hi, lo;
    const float4 a = *(const float4*)(W + (size_t)e * HID + k0);
    const float4 b = *(const float4*)(W + (size_t)e * HID + k0 + 4);
    cvt8(a, b, hi, lo);

    u16* base = Wfrag + (size_t)S * 2048 + (size_t)(e >> 5) * 512 + lane * 8;
    *(bf16x8*)(base)        = hi;     // chunk (e>>5)
    *(bf16x8*)(base + 1024) = lo;     // chunk 2+(e>>5)
}

// ---------------------------------------------------------------------------
// K1: logits via 3-term bf16-split MFMA.  128 TOKENS/BLOCK, 16 waves.
// Wave = (kq, et, tt) = (K-half, expert-tile, token-tile/4); each wave owns
// one 32x32 C-quadrant (acc = 16 VGPR).  Chunk = 64k: A [128tok][64f] 32KB
// + W 16KB, TRIPLE-buffered (144KB LDS, grid 256 = 1 block/CU, 16 waves/CU
// — same wave residency as r11 but W bytes amortized over 2x tokens:
// chip W traffic 256 -> 128 MB, per-CU VMEM 2.0 -> 1.5 MB).
// Counted vmcnt: 3 DMA instrs/wave/chunk; loop vmcnt(6) keeps chunks c+1,c+2
// in flight; peeled tail 6/3/0.  Two barriers/chunk (land / buf-free).
// A source XOR-swizzled slot = g ^ (row&7); LDS dest linear (T2/m173).
// Epilogue: split-K reduce -> logits store -> top-2 -> INLINE fp64 refine
// (fixes r11's refine-after-count ordering hazard) -> fused count.
// ---------------------------------------------------------------------------
__global__ __launch_bounds__(1024, 1) void k_logits(
    const float* __restrict__ A, const u16* __restrict__ Wfrag,
    const float* __restrict__ W, const float* __restrict__ bias,
    float* __restrict__ logits, float* __restrict__ probsmax,
    int* __restrict__ choice, int* __restrict__ cnt)
{
    __shared__ float smem[36864];         // 144 KB: 3 x (A 8192f + W 4096f)
    const int tid  = threadIdx.x;
    const int lane = tid & 63;
    const int wv   = __builtin_amdgcn_readfirstlane(tid >> 6);  // 0..15
    const int kq = wv & 1, et = (wv >> 1) & 1, tt = wv >> 2;
    const int tok0 = blockIdx.x * 128;

    // A DMA: wave stages rows [wv*8, +8) in 2 instrs of 4 rows x 256B.
    // lane slot s=lane&15 holds global granule s^(row&7) (LDS dest linear).
    const int s  = lane & 15;
    const int r0 = wv * 8 + (lane >> 4);
    const int r1 = r0 + 4;
    const float* paA0 = A + (size_t)(tok0 + r0) * HID + ((s ^ (r0 & 7)) << 2);
    const float* paA1 = A + (size_t)(tok0 + r1) * HID + ((s ^ (r1 & 7)) << 2);
    // W DMA: wave stages bytes [wv*1KB, +1KB) of the chunk's 16KB
    const u16* pw = Wfrag + wv * 512 + lane * 8;

    f32x16 acc;
#pragma unroll
    for (int r = 0; r < 16; ++r) acc[r] = 0.0f;

#define MFMA_ __builtin_amdgcn_mfma_f32_32x32x16_bf16
#define DMA(C) {                                                          \
    const int b_ = (C) % 3;                                               \
    float* ab = smem + b_ * 12288;                                        \
    u16*  wb2 = (u16*)(smem + b_ * 12288 + 8192);                         \
    GLOAD_LDS16(paA0 + (C) * 64, ab + (wv * 8) * 64);                     \
    GLOAD_LDS16(paA1 + (C) * 64, ab + (wv * 8 + 4) * 64);                 \
    GLOAD_LDS16(pw + (size_t)(C) * 8192, wb2 + wv * 512); }
#define COMPUTE(C) {                                                      \
    const int b_ = (C) % 3;                                               \
    const int trow = tt * 32 + (lane & 31);                               \
    const float* ab = smem + b_ * 12288 + trow * 64;                      \
    const u16*  wb2 = (const u16*)(smem + b_ * 12288 + 8192);             \
    _Pragma("unroll")                                                     \
    for (int ks = 0; ks < 2; ++ks) {                                      \
        const int g0 = kq * 8 + ks * 4 + (lane >> 5) * 2;                 \
        const float4 va = *(const float4*)(ab + ((g0 ^ (trow & 7)) << 2));\
        const float4 vb = *(const float4*)(ab + (((g0 + 1) ^ (trow & 7)) << 2)); \
        const u16* wp = wb2 + (kq * 2 + ks) * 2048 + et * 512 + lane * 8; \
        const bf16x8 wh = *(const bf16x8*)(wp);                           \
        const bf16x8 wl = *(const bf16x8*)(wp + 1024);                    \
        bf16x8 ah, al; cvt8(va, vb, ah, al);                              \
        acc = MFMA_(wh, ah, acc, 0, 0, 0);                                \
        acc = MFMA_(wl, ah, acc, 0, 0, 0);                                \
        acc = MFMA_(wh, al, acc, 0, 0, 0);                                \
    } }

    // prologue: chunks 0,1,2 in flight (9 DMA instrs per wave)
    DMA(0)
    DMA(1)
    DMA(2)

#pragma unroll 1
    for (int c = 0; c < 29; ++c) {
        asm volatile("s_waitcnt vmcnt(6)" ::: "memory");   // DMA(c) landed
        __builtin_amdgcn_s_barrier();                      // ...for ALL waves
        __builtin_amdgcn_sched_barrier(0);
        COMPUTE(c)
        __builtin_amdgcn_sched_barrier(0);
        __builtin_amdgcn_s_barrier();                      // buf c%3 free
        DMA(c + 3)                                         // overwrite it
    }
    asm volatile("s_waitcnt vmcnt(6)" ::: "memory");
    __builtin_amdgcn_s_barrier();
    __builtin_amdgcn_sched_barrier(0);
    COMPUTE(29)
    asm volatile("s_waitcnt vmcnt(3)" ::: "memory");
    __builtin_amdgcn_s_barrier();
    __builtin_amdgcn_sched_barrier(0);
    COMPUTE(30)
    asm volatile("s_waitcnt vmcnt(0)" ::: "memory");
    __builtin_amdgcn_s_barrier();
    __builtin_amdgcn_sched_barrier(0);
    COMPUTE(31)
#undef COMPUTE
#undef DMA

    __syncthreads();                      // staging done; reuse smem as lacc

    // ---- C-quadrant -> lacc[kq][128 tok][65] (plane stride 8320 floats) ----
    {
        const int trow = tt * 32 + (lane & 31);
        float* pl = smem + kq * 8320 + trow * 65 + et * 32;
#pragma unroll
        for (int r = 0; r < 16; ++r) {
            const int er = (r & 3) + 8 * (r >> 2) + 4 * (lane >> 5);
            pl[er] = acc[r];
        }
    }
    __syncthreads();

    // split-K reduce (+bias), coalesced logits store, stash row into plane 0
    {
        const int t  = tid >> 3;          // 0..127
        const int e0 = (tid & 7) * 8;
        float v[8];
#pragma unroll
        for (int i = 0; i < 8; ++i) {
            const int o = t * 65 + e0 + i;
            v[i] = smem[o] + smem[8320 + o] + bias[e0 + i];
        }
        float* lp = logits + (size_t)(tok0 + t) * NE + e0;
        *(float4*)(lp)     = make_float4(v[0], v[1], v[2], v[3]);
        *(float4*)(lp + 4) = make_float4(v[4], v[5], v[6], v[7]);
#pragma unroll
        for (int i = 0; i < 8; ++i) smem[t * 65 + e0 + i] = v[i];
    }
    __syncthreads();

    // per-token epilogue (2 waves, 128 lanes = 128 tokens): top-2 + softmax
    // denom -> INLINE fp64 refine of near-ties -> choice + fused histogram.
    if (tid < 128) {
        const int t = tid;
        float m1 = -3.4e38f, m2 = -3.4e38f;
        int i1 = 0, i2 = 0;
#pragma unroll
        for (int e = 0; e < NE; ++e) {
            const float vv = smem[t * 65 + e];
            if (vv > m1)      { m2 = m1; i2 = i1; m1 = vv; i1 = e; }
            else if (vv > m2) { m2 = vv; i2 = e; }
        }
        float sden = 0.0f;
#pragma unroll
        for (int e = 0; e < NE; ++e)
            sden += __expf(smem[t * 65 + e] - m1);
        const int g2 = tok0 + t;
        probsmax[g2] = 1.0f / sden;       // max prob = exp(0)/sum

        // ---- wave-cooperative fp64 refine (before counting!) ----
        const bool flag = (m1 - m2 < GAP_THR) && (i1 != i2);
        unsigned long long msk = __ballot(flag);
        const int wtbase = tok0 + (tid >> 6) * 64;
        while (msk) {
            const int tt2 = (int)__ffsll((long long)msk) - 1;
            msk &= msk - 1;
            const int i1t = __shfl(i1, tt2);
            const int i2t = __shfl(i2, tt2);
            const float* a2 = A + (size_t)(wtbase + tt2) * HID;
            const float* w1 = W + (size_t)i1t * HID;
            const float* w2 = W + (size_t)i2t * HID;
            double d1 = 0.0, d2 = 0.0;
#pragma unroll 4
            for (int h = lane; h < HID; h += 64) {
                const double av = (double)a2[h];
                d1 += av * (double)w1[h];
                d2 += av * (double)w2[h];
            }
#pragma unroll
            for (int o = 32; o; o >>= 1) {
                d1 += __shfl_xor(d1, o);
                d2 += __shfl_xor(d2, o);
            }
            d1 += (double)bias[i1t];
            d2 += (double)bias[i2t];
            if (lane == tt2 && (d2 > d1 || (d2 == d1 && i2t < i1t))) i1 = i2t;
        }
        choice[g2] = i1;

        // fused per-64-token-chunk histogram (uses REFINED choice)
        int mycnt = 0;
#pragma unroll 1
        for (int e = 0; e < NE; ++e) {
            const unsigned long long m = __ballot(i1 == e);
            if (lane == e) mycnt = (int)__popcll(m);
        }
        cnt[(blockIdx.x * 2 + (tid >> 6)) * 64 + lane] = mycnt;
    }
}

// ---------------------------------------------------------------------------
// K3: exclusive scan of 128 chunk-histograms per group, staged in LDS.
// (chunk = 64 tokens; 512 chunks total, 128/group; no group straddle)
// ---------------------------------------------------------------------------
__global__ __launch_bounds__(256) void k_scan(const int* __restrict__ cnt,
                                              int* __restrict__ off)
{
    __shared__ int sm[128 * 64];      // 32 KB
    const int tid  = threadIdx.x;
    const int base = blockIdx.x * 128 * 64;
#pragma unroll
    for (int i = 0; i < 32; ++i)
        sm[tid + 256 * i] = cnt[base + tid + 256 * i];
    __syncthreads();
    if (tid < 64) {
        int run = 0;
#pragma unroll 1
        for (int c = 0; c < 128; ++c) {
            const int idx = c * 64 + tid;
            const int v = sm[idx];
            sm[idx] = run;
            run += v;
        }
    }
    __syncthreads();
#pragma unroll
    for (int i = 0; i < 32; ++i)
        off[base + tid + 256 * i] = sm[tid + 256 * i];
}

// ---------------------------------------------------------------------------
// K4: emit expert_index rows (0/1 as fp32) with capacity mask.
// ---------------------------------------------------------------------------
__global__ void k_emit(const int* __restrict__ choice, const int* __restrict__ off,
                       float* __restrict__ eout)
{
    const int lane  = threadIdx.x & 63;
    const int wave  = threadIdx.x >> 6;
    const int chunk = blockIdx.x * 4 + wave;
    const int gt    = chunk * 64 + lane;
    const int c     = choice[gt];
    unsigned long long mymask = 0;
#pragma unroll 1
    for (int e = 0; e < NE; ++e) {
        const unsigned long long m = __ballot(c == e);
        if (c == e) mymask = m;
    }
    const int pre  = (int)__popcll(mymask & ((1ull << lane) - 1ull));
    const int base = off[chunk * 64 + c];
    const float val = (base + pre + 1 <= CAP) ? 1.0f : 0.0f;
    float* op = eout + (size_t)gt * NE;
#pragma unroll
    for (int i = 0; i < 16; ++i) {
        float4 v;
        v.x = (4*i+0 == c) ? val : 0.0f;
        v.y = (4*i+1 == c) ? val : 0.0f;
        v.z = (4*i+2 == c) ? val : 0.0f;
        v.w = (4*i+3 == c) ? val : 0.0f;
        ((float4*)op)[i] = v;
    }
}

// ---------------------------------------------------------------------------
extern "C" void kernel_launch(void* const* d_in, const int* in_sizes, int n_in,
                              void* d_out, int out_size, void* d_ws, size_t ws_size,
                              hipStream_t stream) {
    const float* A = (const float*)d_in[0];   // [4, 8192, 2048]
    const float* W = (const float*)d_in[1];   // [64, 2048]
    const float* b = (const float*)d_in[2];   // [64]

    float* out        = (float*)d_out;
    float* expert_out = out;                        // 2,097,152
    float* probsmax   = out + 2097152;              //    32,768
    float* logits     = out + 2097152 + 32768;      // 2,097,152

    char* ws      = (char*)d_ws;
    int*   choice = (int*)(ws);                 // 128 KB
    int*   cnt    = (int*)(ws + 131072);        // 128 KB
    int*   off    = (int*)(ws + 262144);        // 128 KB
    u16*   Wfrag  = (u16*)(ws + 393216);        // 512 KB fragment-major

    hipLaunchKernelGGL(k_wconv, dim3(64), dim3(256), 0, stream, W, Wfrag);
    hipLaunchKernelGGL(k_logits, dim3(256), dim3(1024), 0, stream,
                       A, Wfrag, W, b, logits, probsmax, choice, cnt);
    hipLaunchKernelGGL(k_scan, dim3(4), dim3(256), 0, stream, cnt, off);
    hipLaunchKernelGGL(k_emit, dim3(128), dim3(256), 0, stream, choice, off, expert_out);
}